// Round 7
// baseline (197.608 us; speedup 1.0000x reference)
//
#include <hip/hip_runtime.h>
#include <hip/hip_bf16.h>

#define NB   4
#define NC   256
#define NPOS 4096
#define NDQK 32

typedef __bf16 bf16x8  __attribute__((ext_vector_type(8)));
typedef float  f32x16  __attribute__((ext_vector_type(16)));

typedef __attribute__((address_space(3))) char*       lds_ptr_t;
typedef const __attribute__((address_space(1))) char* glb_ptr_t;

// =====================================================================
// Projection: Y[o][n] = sum_c W[o][c] x[c][n] + b[o], bf16 MFMA.
// Item = (b, g, nch64): g<4 -> V row-pairs (o0=g*64, o1=g*64+32);
// g==4 -> Q (A0, pre-scaled log2e on store) and K (A1).
// Each x B-frag (8 scalar loads) feeds TWO MFMAs (halves x traffic).
// =====================================================================
__global__ __launch_bounds__(256) void proj_kernel(
    const float* __restrict__ x,
    const float* __restrict__ Wq, const float* __restrict__ bq,
    const float* __restrict__ Wk, const float* __restrict__ bk,
    const float* __restrict__ Wv, const float* __restrict__ bv,
    __hip_bfloat16* __restrict__ Qb, __hip_bfloat16* __restrict__ Kb,
    __hip_bfloat16* __restrict__ Vb)
{
    const int t   = threadIdx.x;
    const int l   = t & 63;
    const int w   = t >> 6;
    const int hi  = l >> 5;
    const int col = l & 31;
    const int row = l & 31;

    const int item = blockIdx.x * 4 + w;     // 0..1279
    const int nch  = item & 63;              // 64-n chunk
    const int rest = item >> 6;              // 0..19
    const int g    = rest % 5;
    const int b    = rest / 5;

    const float *W0, *W1, *bs0, *bs1;
    int o0 = 0, o1 = 0;
    if (g < 4) {
        o0 = g * 64; o1 = g * 64 + 32;
        W0 = Wv + (size_t)o0 * NC; W1 = Wv + (size_t)o1 * NC;
        bs0 = bv + o0; bs1 = bv + o1;
    } else {
        W0 = Wq; W1 = Wk; bs0 = bq; bs1 = bk;
    }

    bf16x8 wf0[16], wf1[16];
    const float* Wr0 = W0 + (size_t)row * NC + 8 * hi;
    const float* Wr1 = W1 + (size_t)row * NC + 8 * hi;
    #pragma unroll
    for (int kk = 0; kk < 16; ++kk) {
        float4 a0 = *reinterpret_cast<const float4*>(Wr0 + kk * 16);
        float4 c0 = *reinterpret_cast<const float4*>(Wr0 + kk * 16 + 4);
        float4 a1 = *reinterpret_cast<const float4*>(Wr1 + kk * 16);
        float4 c1 = *reinterpret_cast<const float4*>(Wr1 + kk * 16 + 4);
        bf16x8 f0, f1;
        f0[0] = (__bf16)a0.x; f0[1] = (__bf16)a0.y; f0[2] = (__bf16)a0.z; f0[3] = (__bf16)a0.w;
        f0[4] = (__bf16)c0.x; f0[5] = (__bf16)c0.y; f0[6] = (__bf16)c0.z; f0[7] = (__bf16)c0.w;
        f1[0] = (__bf16)a1.x; f1[1] = (__bf16)a1.y; f1[2] = (__bf16)a1.z; f1[3] = (__bf16)a1.w;
        f1[4] = (__bf16)c1.x; f1[5] = (__bf16)c1.y; f1[6] = (__bf16)c1.z; f1[7] = (__bf16)c1.w;
        wf0[kk] = f0; wf1[kk] = f1;
    }

    #pragma unroll 1
    for (int tile = 0; tile < 2; ++tile) {
        const int n0 = nch * 64 + tile * 32;
        f32x16 acc0, acc1;
        #pragma unroll
        for (int r = 0; r < 16; ++r) { acc0[r] = 0.f; acc1[r] = 0.f; }

        const float* xcol = x + (size_t)b * NC * NPOS + n0 + col;
        #pragma unroll
        for (int kk = 0; kk < 16; ++kk) {
            bf16x8 bf;
            #pragma unroll
            for (int i = 0; i < 8; ++i)
                bf[i] = (__bf16)xcol[(size_t)(kk * 16 + 8 * hi + i) * NPOS];
            acc0 = __builtin_amdgcn_mfma_f32_32x32x16_bf16(wf0[kk], bf, acc0, 0, 0, 0);
            acc1 = __builtin_amdgcn_mfma_f32_32x32x16_bf16(wf1[kk], bf, acc1, 0, 0, 0);
        }

        if (g < 4) {
            #pragma unroll
            for (int r = 0; r < 16; ++r) {
                const int orow = (r & 3) + 8 * (r >> 2) + 4 * hi;
                Vb[((size_t)(b * NC + o0 + orow)) * NPOS + n0 + col] =
                    __float2bfloat16(acc0[r] + bs0[orow]);
                Vb[((size_t)(b * NC + o1 + orow)) * NPOS + n0 + col] =
                    __float2bfloat16(acc1[r] + bs1[orow]);
            }
        } else {
            #pragma unroll
            for (int r = 0; r < 16; ++r) {
                const int orow = (r & 3) + 8 * (r >> 2) + 4 * hi;
                const size_t nidx = (size_t)(b * NPOS) + n0 + col;
                Qb[nidx * NDQK + orow] =
                    __float2bfloat16((acc0[r] + bs0[orow]) * 1.44269504088896f);
                Kb[nidx * NDQK + orow] =
                    __float2bfloat16(acc1[r] + bs1[orow]);
            }
        }
    }
}

// =====================================================================
// Fused flash attention + residual, 32x32x16 MFMA, linear softmax
// (exp2, log2e folded into Q; no online max at |S|<~50).
//
// Wave = 32 q x 64 ch, block = 4 waves (c-split), fully wave-private.
// V staged global->LDS; buffer layout [4 j-chunks][64 c][16B]: each DMA
// instr writes one chunk (lane = c), each ds_read_b128 walks 16B stride
// -> conflict-free by construction, no swizzle.
// VMEM order per iter: [K-next loads][STAGE(T+2)][vmcnt(12)] — K before
// STAGE so the compiler's auto-wait for K never drains the prefetch
// queue (the r4-r6 serializer). Counted waits: 12 newer VMEM ops always
// precede STAGE(T)'s wait. No __syncthreads anywhere.
// =====================================================================
__global__ __launch_bounds__(256, 2) void attn_kernel(
    const __hip_bfloat16* __restrict__ Qb,
    const __hip_bfloat16* __restrict__ Kb,
    const __hip_bfloat16* __restrict__ Vb,
    const float* __restrict__ x,
    const float* __restrict__ gamma,
    float* __restrict__ out)
{
    __shared__ __align__(16) char smem[65536];   // 4 waves x 4 bufs x 4KB
    const int t   = threadIdx.x;
    const int l   = t & 63;
    const int w   = t >> 6;
    const int hi  = l >> 5;
    const int q   = l & 31;
    const int bx  = blockIdx.x;
    const int b   = (bx >> 1) & 3;               // XCD-pair -> one batch
    const int qb  = ((bx >> 3) << 1) | (bx & 1); // 0..127
    const int q0  = qb * 32;
    const int c0w = w * 64;

    const __bf16* Qp = reinterpret_cast<const __bf16*>(Qb) + (size_t)b * NPOS * NDQK;
    const __bf16* Kp = reinterpret_cast<const __bf16*>(Kb) + (size_t)b * NPOS * NDQK;
    const __bf16* Vp = reinterpret_cast<const __bf16*>(Vb) + (size_t)b * NC * NPOS;

    // swap bits 2<->3 of the A-row index so S lands exactly in PV B-frag order
    const int perm = (q & 0x13) | ((q & 4) << 1) | ((q & 8) >> 1);

    const bf16x8 qf0 = *reinterpret_cast<const bf16x8*>(Qp + (size_t)(q0 + q) * NDQK + 8 * hi);
    const bf16x8 qf1 = *reinterpret_cast<const bf16x8*>(Qp + (size_t)(q0 + q) * NDQK + 16 + 8 * hi);

    const __bf16* Kbase = Kp + (size_t)perm * NDQK + 8 * hi;

    // V staging: buffer = [4 chunks][64 c][8 j elems]; DMA instr i writes
    // chunk i (lane l -> row c0w+l, 16B at j0 + i*8). Read: 16B stride.
    __bf16* vb = reinterpret_cast<__bf16*>(smem) + w * 8192;  // [4][2048] elems
    const __bf16* vsrc = Vp + (size_t)(c0w + l) * NPOS;

    #define STAGE(buf, j0_) do {                                                        \
        __builtin_amdgcn_global_load_lds((glb_ptr_t)(const char*)(vsrc + (j0_)),        \
            (lds_ptr_t)(char*)(vb + (buf) * 2048),        16, 0, 0);                    \
        __builtin_amdgcn_global_load_lds((glb_ptr_t)(const char*)(vsrc + (j0_) + 8),    \
            (lds_ptr_t)(char*)(vb + (buf) * 2048 + 512),  16, 0, 0);                    \
        __builtin_amdgcn_global_load_lds((glb_ptr_t)(const char*)(vsrc + (j0_) + 16),   \
            (lds_ptr_t)(char*)(vb + (buf) * 2048 + 1024), 16, 0, 0);                    \
        __builtin_amdgcn_global_load_lds((glb_ptr_t)(const char*)(vsrc + (j0_) + 24),   \
            (lds_ptr_t)(char*)(vb + (buf) * 2048 + 1536), 16, 0, 0);                    \
    } while (0)

    const int cl0 = l & 31;

    f32x16 acc0, acc1;
    #pragma unroll
    for (int r = 0; r < 16; ++r) { acc0[r] = 0.f; acc1[r] = 0.f; }
    float lp = 0.f;

    // prologue: tiles 0,1 in flight, then K tile 0 (AFTER stages in issue order)
    STAGE(0, 0);
    STAGE(1, 32);
    asm volatile("" ::: "memory");
    bf16x8 kc0 = *reinterpret_cast<const bf16x8*>(Kbase);
    bf16x8 kc1 = *reinterpret_cast<const bf16x8*>(Kbase + 16);

    #pragma unroll 2
    for (int jt = 0; jt < 128; ++jt) {
        const int j0 = jt * 32;

        // K prefetch for next tile — BEFORE this iteration's STAGE
        bf16x8 kn0 = kc0, kn1 = kc1;
        if (jt < 127) {
            kn0 = *reinterpret_cast<const bf16x8*>(Kbase + (size_t)(j0 + 32) * NDQK);
            kn1 = *reinterpret_cast<const bf16x8*>(Kbase + (size_t)(j0 + 32) * NDQK + 16);
        }
        asm volatile("" ::: "memory");           // pin K before STAGE
        if (jt < 126) {
            STAGE((jt + 2) & 3, j0 + 64);
            asm volatile("s_waitcnt vmcnt(12)" ::: "memory");
        } else if (jt == 126) {
            asm volatile("s_waitcnt vmcnt(8)" ::: "memory");
        } else {
            asm volatile("s_waitcnt vmcnt(0)" ::: "memory");
        }

        const __bf16* vcur = vb + (jt & 3) * 2048;
        const bf16x8 vf00 = *reinterpret_cast<const bf16x8*>(vcur + hi * 512 + cl0 * 8);
        const bf16x8 vf01 = *reinterpret_cast<const bf16x8*>(vcur + (2 + hi) * 512 + cl0 * 8);
        const bf16x8 vf10 = *reinterpret_cast<const bf16x8*>(vcur + hi * 512 + 256 + cl0 * 8);
        const bf16x8 vf11 = *reinterpret_cast<const bf16x8*>(vcur + (2 + hi) * 512 + 256 + cl0 * 8);

        f32x16 s;
        #pragma unroll
        for (int r = 0; r < 16; ++r) s[r] = 0.f;
        s = __builtin_amdgcn_mfma_f32_32x32x16_bf16(kc0, qf0, s, 0, 0, 0);
        s = __builtin_amdgcn_mfma_f32_32x32x16_bf16(kc1, qf1, s, 0, 0, 0);

        float p[16];
        #pragma unroll
        for (int r = 0; r < 16; ++r) p[r] = __builtin_amdgcn_exp2f(s[r]);

        const float s0 = (p[0] + p[1]) + (p[2] + p[3]);
        const float s1 = (p[4] + p[5]) + (p[6] + p[7]);
        const float s2 = (p[8] + p[9]) + (p[10] + p[11]);
        const float s3 = (p[12] + p[13]) + (p[14] + p[15]);
        lp += (s0 + s1) + (s2 + s3);

        bf16x8 pa0, pa1;
        #pragma unroll
        for (int i = 0; i < 8; ++i) { pa0[i] = (__bf16)p[i]; pa1[i] = (__bf16)p[8 + i]; }

        acc0 = __builtin_amdgcn_mfma_f32_32x32x16_bf16(vf00, pa0, acc0, 0, 0, 0);
        acc0 = __builtin_amdgcn_mfma_f32_32x32x16_bf16(vf01, pa1, acc0, 0, 0, 0);
        acc1 = __builtin_amdgcn_mfma_f32_32x32x16_bf16(vf10, pa0, acc1, 0, 0, 0);
        acc1 = __builtin_amdgcn_mfma_f32_32x32x16_bf16(vf11, pa1, acc1, 0, 0, 0);

        kc0 = kn0;
        kc1 = kn1;
    }
    #undef STAGE

    // epilogue: l is lane-local per q after one shfl; direct fused store
    const float lt = lp + __shfl_xor(lp, 32);
    const float gl = gamma[0] / lt;

    #pragma unroll
    for (int r = 0; r < 16; ++r) {
        const int crow = (r & 3) + 8 * (r >> 2) + 4 * hi;
        const size_t g0 = ((size_t)(b * NC + c0w + crow)) * NPOS + q0 + q;
        const size_t g1 = g0 + (size_t)32 * NPOS;
        out[g0] = x[g0] + gl * acc0[r];
        out[g1] = x[g1] + gl * acc1[r];
    }
}

extern "C" void kernel_launch(void* const* d_in, const int* in_sizes, int n_in,
                              void* d_out, int out_size, void* d_ws, size_t ws_size,
                              hipStream_t stream) {
    (void)in_sizes; (void)n_in; (void)out_size; (void)ws_size;
    const float* x     = (const float*)d_in[0];
    const float* Wq    = (const float*)d_in[1];
    const float* bq    = (const float*)d_in[2];
    const float* Wk    = (const float*)d_in[3];
    const float* bk    = (const float*)d_in[4];
    const float* Wv    = (const float*)d_in[5];
    const float* bv    = (const float*)d_in[6];
    const float* gamma = (const float*)d_in[7];
    float* out = (float*)d_out;

    char* ws = (char*)d_ws;
    __hip_bfloat16* Qb = (__hip_bfloat16*)(ws);                    // 1 MB
    __hip_bfloat16* Kb = (__hip_bfloat16*)(ws + (1u << 20));       // 1 MB
    __hip_bfloat16* Vb = (__hip_bfloat16*)(ws + (2u << 20));       // 8 MB

    proj_kernel<<<320, 256, 0, stream>>>(x, Wq, bq, Wk, bk, Wv, bv, Qb, Kb, Vb);
    attn_kernel<<<512, 256, 0, stream>>>(Qb, Kb, Vb, x, gamma, out);
}

// Round 8
// 122.225 us; speedup vs baseline: 1.6168x; 1.6168x over previous
//
#include <hip/hip_runtime.h>
#include <hip/hip_bf16.h>

#define NB   4
#define NC   256
#define NPOS 4096
#define NDQK 32

typedef __bf16 bf16x8  __attribute__((ext_vector_type(8)));
typedef float  f32x16  __attribute__((ext_vector_type(16)));

typedef __attribute__((address_space(3))) char*       lds_ptr_t;
typedef const __attribute__((address_space(1))) char* glb_ptr_t;

// V layout: tiled [b][jt=NPOS/32][c=NC][j'=32] bf16 — a wave's 64c x 32j
// tile is 4KB contiguous, so attention staging is fully coalesced.

// =====================================================================
// Projection: Y[o][n] = sum_c W[o][c] x[c][n] + b[o], bf16 MFMA.
// Item = (b, g, nch64): g<4 -> V row-pairs (o0=g*64, o1=g*64+32);
// g==4 -> Q (A0, pre-scaled log2e on store) and K (A1).
// Each x B-frag (8 scalar loads) feeds TWO MFMAs.
// =====================================================================
__global__ __launch_bounds__(256) void proj_kernel(
    const float* __restrict__ x,
    const float* __restrict__ Wq, const float* __restrict__ bq,
    const float* __restrict__ Wk, const float* __restrict__ bk,
    const float* __restrict__ Wv, const float* __restrict__ bv,
    __hip_bfloat16* __restrict__ Qb, __hip_bfloat16* __restrict__ Kb,
    __hip_bfloat16* __restrict__ Vb)
{
    const int t   = threadIdx.x;
    const int l   = t & 63;
    const int w   = t >> 6;
    const int hi  = l >> 5;
    const int col = l & 31;
    const int row = l & 31;

    const int item = blockIdx.x * 4 + w;     // 0..1279
    const int nch  = item & 63;              // 64-n chunk
    const int rest = item >> 6;              // 0..19
    const int g    = rest % 5;
    const int b    = rest / 5;

    const float *W0, *W1, *bs0, *bs1;
    int o0 = 0, o1 = 0;
    if (g < 4) {
        o0 = g * 64; o1 = g * 64 + 32;
        W0 = Wv + (size_t)o0 * NC; W1 = Wv + (size_t)o1 * NC;
        bs0 = bv + o0; bs1 = bv + o1;
    } else {
        W0 = Wq; W1 = Wk; bs0 = bq; bs1 = bk;
    }

    bf16x8 wf0[16], wf1[16];
    const float* Wr0 = W0 + (size_t)row * NC + 8 * hi;
    const float* Wr1 = W1 + (size_t)row * NC + 8 * hi;
    #pragma unroll
    for (int kk = 0; kk < 16; ++kk) {
        float4 a0 = *reinterpret_cast<const float4*>(Wr0 + kk * 16);
        float4 c0 = *reinterpret_cast<const float4*>(Wr0 + kk * 16 + 4);
        float4 a1 = *reinterpret_cast<const float4*>(Wr1 + kk * 16);
        float4 c1 = *reinterpret_cast<const float4*>(Wr1 + kk * 16 + 4);
        bf16x8 f0, f1;
        f0[0] = (__bf16)a0.x; f0[1] = (__bf16)a0.y; f0[2] = (__bf16)a0.z; f0[3] = (__bf16)a0.w;
        f0[4] = (__bf16)c0.x; f0[5] = (__bf16)c0.y; f0[6] = (__bf16)c0.z; f0[7] = (__bf16)c0.w;
        f1[0] = (__bf16)a1.x; f1[1] = (__bf16)a1.y; f1[2] = (__bf16)a1.z; f1[3] = (__bf16)a1.w;
        f1[4] = (__bf16)c1.x; f1[5] = (__bf16)c1.y; f1[6] = (__bf16)c1.z; f1[7] = (__bf16)c1.w;
        wf0[kk] = f0; wf1[kk] = f1;
    }

    #pragma unroll 1
    for (int tile = 0; tile < 2; ++tile) {
        const int n0 = nch * 64 + tile * 32;
        f32x16 acc0, acc1;
        #pragma unroll
        for (int r = 0; r < 16; ++r) { acc0[r] = 0.f; acc1[r] = 0.f; }

        const float* xcol = x + (size_t)b * NC * NPOS + n0 + col;
        #pragma unroll
        for (int kk = 0; kk < 16; ++kk) {
            bf16x8 bf;
            #pragma unroll
            for (int i = 0; i < 8; ++i)
                bf[i] = (__bf16)xcol[(size_t)(kk * 16 + 8 * hi + i) * NPOS];
            acc0 = __builtin_amdgcn_mfma_f32_32x32x16_bf16(wf0[kk], bf, acc0, 0, 0, 0);
            acc1 = __builtin_amdgcn_mfma_f32_32x32x16_bf16(wf1[kk], bf, acc1, 0, 0, 0);
        }

        if (g < 4) {
            // tiled V store: [b][jt][c][j'], j' = col (64B contiguous/row)
            __hip_bfloat16* vt = Vb + (size_t)b * NC * NPOS
                                    + (size_t)(n0 >> 5) * (NC * 32) + col;
            #pragma unroll
            for (int r = 0; r < 16; ++r) {
                const int orow = (r & 3) + 8 * (r >> 2) + 4 * hi;
                vt[(size_t)(o0 + orow) * 32] = __float2bfloat16(acc0[r] + bs0[orow]);
                vt[(size_t)(o1 + orow) * 32] = __float2bfloat16(acc1[r] + bs1[orow]);
            }
        } else {
            #pragma unroll
            for (int r = 0; r < 16; ++r) {
                const int orow = (r & 3) + 8 * (r >> 2) + 4 * hi;
                const size_t nidx = (size_t)(b * NPOS) + n0 + col;
                Qb[nidx * NDQK + orow] =
                    __float2bfloat16((acc0[r] + bs0[orow]) * 1.44269504088896f);
                Kb[nidx * NDQK + orow] =
                    __float2bfloat16(acc1[r] + bs1[orow]);
            }
        }
    }
}

// =====================================================================
// Fused flash attention + residual, 32x32x16 MFMA, linear softmax
// (exp2, log2e folded into Q; no online max at |S|<~50).
//
// Wave = 32 q x 64 ch, block = 4 waves (c-split), wave-private V tiles.
// V staged via global_load_lds from the TILED layout: each instruction
// reads 1KB CONTIGUOUS (16 rows x 64B, chunk-permuted within 4-lane
// groups). LDS holds chunk c4 of row r at physical slot c4 ^ ((r>>1)&3)
// -> ds_read_b128 (32 lanes, rows 0..31, fixed chunk) covers all 32
// banks per 8-lane phase: conflict-free. Source pre-applies the inverse
// swizzle (G21 both-sides rule): lane l -> row l>>2, chunk (l&3)^((l>>3)&3).
// 4 buffers, 2 tiles ahead, counted vmcnt(12). K prefetched one tile
// ahead and issued BEFORE STAGE so the compiler's auto-wait for K is
// vmcnt(~10), never a queue drain. No __syncthreads anywhere.
// =====================================================================
__global__ __launch_bounds__(256, 2) void attn_kernel(
    const __hip_bfloat16* __restrict__ Qb,
    const __hip_bfloat16* __restrict__ Kb,
    const __hip_bfloat16* __restrict__ Vb,
    const float* __restrict__ x,
    const float* __restrict__ gamma,
    float* __restrict__ out)
{
    __shared__ __align__(16) char smem[65536];   // 4 waves x 4 bufs x 4KB
    const int t   = threadIdx.x;
    const int l   = t & 63;
    const int w   = t >> 6;
    const int hi  = l >> 5;
    const int q   = l & 31;
    const int bx  = blockIdx.x;
    const int b   = (bx >> 1) & 3;               // XCD-pair -> one batch
    const int qb  = ((bx >> 3) << 1) | (bx & 1); // 0..127
    const int q0  = qb * 32;
    const int c0w = w * 64;

    const __bf16* Qp = reinterpret_cast<const __bf16*>(Qb) + (size_t)b * NPOS * NDQK;
    const __bf16* Kp = reinterpret_cast<const __bf16*>(Kb) + (size_t)b * NPOS * NDQK;
    const __bf16* Vp = reinterpret_cast<const __bf16*>(Vb) + (size_t)b * NC * NPOS;

    // swap bits 2<->3 of the A-row index so S lands exactly in PV B-frag order
    const int perm = (q & 0x13) | ((q & 4) << 1) | ((q & 8) >> 1);

    const bf16x8 qf0 = *reinterpret_cast<const bf16x8*>(Qp + (size_t)(q0 + q) * NDQK + 8 * hi);
    const bf16x8 qf1 = *reinterpret_cast<const bf16x8*>(Qp + (size_t)(q0 + q) * NDQK + 16 + 8 * hi);

    const __bf16* Kbase = Kp + (size_t)perm * NDQK + 8 * hi;

    // V staging source: tiled layout, wave's region = [c0w..c0w+64) x 32j = 4KB
    // contiguous per jt. Lane l: row l>>2, inverse-swizzled chunk.
    __bf16* vb = reinterpret_cast<__bf16*>(smem) + w * 8192;  // [4 bufs][2048]
    const int  cswz = (l & 3) ^ ((l >> 3) & 3);
    const __bf16* vsrc = Vp + (size_t)c0w * 32 + (l >> 2) * 32 + cswz * 8;

    #define STAGE(buf, jt_) do {                                                        \
        const __bf16* s_ = vsrc + (size_t)(jt_) * (NC * 32);                            \
        __builtin_amdgcn_global_load_lds((glb_ptr_t)(const char*)(s_),                  \
            (lds_ptr_t)(char*)(vb + (buf) * 2048),        16, 0, 0);                    \
        __builtin_amdgcn_global_load_lds((glb_ptr_t)(const char*)(s_ + 512),            \
            (lds_ptr_t)(char*)(vb + (buf) * 2048 + 512),  16, 0, 0);                    \
        __builtin_amdgcn_global_load_lds((glb_ptr_t)(const char*)(s_ + 1024),           \
            (lds_ptr_t)(char*)(vb + (buf) * 2048 + 1024), 16, 0, 0);                    \
        __builtin_amdgcn_global_load_lds((glb_ptr_t)(const char*)(s_ + 1536),           \
            (lds_ptr_t)(char*)(vb + (buf) * 2048 + 1536), 16, 0, 0);                    \
    } while (0)

    // read offsets: row cl0 (+32 via +1024), logical chunk hi / 2+hi,
    // physical chunk = logical ^ ((row>>1)&3)  (row>>1 mod 4 == cl0>>1 mod 4)
    const int cl0 = l & 31;
    const int sw  = (cl0 >> 1) & 3;
    const int ch0 = (hi ^ sw) * 8;
    const int ch1 = (((2 + hi)) ^ sw) * 8;
    const int ro  = cl0 * 32;

    f32x16 acc0, acc1;
    #pragma unroll
    for (int r = 0; r < 16; ++r) { acc0[r] = 0.f; acc1[r] = 0.f; }
    float lp = 0.f;

    // prologue: tiles 0,1 in flight; K tile 0 issued after (stays newest)
    STAGE(0, 0);
    STAGE(1, 1);
    asm volatile("" ::: "memory");
    bf16x8 kc0 = *reinterpret_cast<const bf16x8*>(Kbase);
    bf16x8 kc1 = *reinterpret_cast<const bf16x8*>(Kbase + 16);

    #pragma unroll 2
    for (int jt = 0; jt < 128; ++jt) {
        const int j0 = jt * 32;

        // K prefetch for next tile — BEFORE this iteration's STAGE
        bf16x8 kn0 = kc0, kn1 = kc1;
        if (jt < 127) {
            kn0 = *reinterpret_cast<const bf16x8*>(Kbase + (size_t)(j0 + 32) * NDQK);
            kn1 = *reinterpret_cast<const bf16x8*>(Kbase + (size_t)(j0 + 32) * NDQK + 16);
        }
        asm volatile("" ::: "memory");           // pin K before STAGE
        if (jt < 126) {
            STAGE((jt + 2) & 3, jt + 2);
            asm volatile("s_waitcnt vmcnt(12)" ::: "memory");
        } else if (jt == 126) {
            asm volatile("s_waitcnt vmcnt(8)" ::: "memory");
        } else {
            asm volatile("s_waitcnt vmcnt(0)" ::: "memory");
        }

        const __bf16* vcur = vb + (jt & 3) * 2048;
        const bf16x8 vf00 = *reinterpret_cast<const bf16x8*>(vcur + ro + ch0);
        const bf16x8 vf01 = *reinterpret_cast<const bf16x8*>(vcur + ro + ch1);
        const bf16x8 vf10 = *reinterpret_cast<const bf16x8*>(vcur + 1024 + ro + ch0);
        const bf16x8 vf11 = *reinterpret_cast<const bf16x8*>(vcur + 1024 + ro + ch1);

        f32x16 s;
        #pragma unroll
        for (int r = 0; r < 16; ++r) s[r] = 0.f;
        s = __builtin_amdgcn_mfma_f32_32x32x16_bf16(kc0, qf0, s, 0, 0, 0);
        s = __builtin_amdgcn_mfma_f32_32x32x16_bf16(kc1, qf1, s, 0, 0, 0);

        float p[16];
        #pragma unroll
        for (int r = 0; r < 16; ++r) p[r] = __builtin_amdgcn_exp2f(s[r]);

        const float s0 = (p[0] + p[1]) + (p[2] + p[3]);
        const float s1 = (p[4] + p[5]) + (p[6] + p[7]);
        const float s2 = (p[8] + p[9]) + (p[10] + p[11]);
        const float s3 = (p[12] + p[13]) + (p[14] + p[15]);
        lp += (s0 + s1) + (s2 + s3);

        bf16x8 pa0, pa1;
        #pragma unroll
        for (int i = 0; i < 8; ++i) { pa0[i] = (__bf16)p[i]; pa1[i] = (__bf16)p[8 + i]; }

        acc0 = __builtin_amdgcn_mfma_f32_32x32x16_bf16(vf00, pa0, acc0, 0, 0, 0);
        acc0 = __builtin_amdgcn_mfma_f32_32x32x16_bf16(vf01, pa1, acc0, 0, 0, 0);
        acc1 = __builtin_amdgcn_mfma_f32_32x32x16_bf16(vf10, pa0, acc1, 0, 0, 0);
        acc1 = __builtin_amdgcn_mfma_f32_32x32x16_bf16(vf11, pa1, acc1, 0, 0, 0);

        kc0 = kn0;
        kc1 = kn1;
    }
    #undef STAGE

    // epilogue: l is lane-local per q after one shfl; direct fused store
    const float lt = lp + __shfl_xor(lp, 32);
    const float gl = gamma[0] / lt;

    #pragma unroll
    for (int r = 0; r < 16; ++r) {
        const int crow = (r & 3) + 8 * (r >> 2) + 4 * hi;
        const size_t g0 = ((size_t)(b * NC + c0w + crow)) * NPOS + q0 + q;
        const size_t g1 = g0 + (size_t)32 * NPOS;
        out[g0] = x[g0] + gl * acc0[r];
        out[g1] = x[g1] + gl * acc1[r];
    }
}

extern "C" void kernel_launch(void* const* d_in, const int* in_sizes, int n_in,
                              void* d_out, int out_size, void* d_ws, size_t ws_size,
                              hipStream_t stream) {
    (void)in_sizes; (void)n_in; (void)out_size; (void)ws_size;
    const float* x     = (const float*)d_in[0];
    const float* Wq    = (const float*)d_in[1];
    const float* bq    = (const float*)d_in[2];
    const float* Wk    = (const float*)d_in[3];
    const float* bk    = (const float*)d_in[4];
    const float* Wv    = (const float*)d_in[5];
    const float* bv    = (const float*)d_in[6];
    const float* gamma = (const float*)d_in[7];
    float* out = (float*)d_out;

    char* ws = (char*)d_ws;
    __hip_bfloat16* Qb = (__hip_bfloat16*)(ws);                    // 1 MB
    __hip_bfloat16* Kb = (__hip_bfloat16*)(ws + (1u << 20));       // 1 MB
    __hip_bfloat16* Vb = (__hip_bfloat16*)(ws + (2u << 20));       // 8 MB (tiled)

    proj_kernel<<<320, 256, 0, stream>>>(x, Wq, bq, Wk, bk, Wv, bv, Qb, Kb, Vb);
    attn_kernel<<<512, 256, 0, stream>>>(Qb, Kb, Vb, x, gamma, out);
}

// Round 9
// 116.130 us; speedup vs baseline: 1.7016x; 1.0525x over previous
//
#include <hip/hip_runtime.h>
#include <hip/hip_bf16.h>

#define NB   4
#define NC   256
#define NPOS 4096
#define NDQK 32

typedef __bf16 bf16x8  __attribute__((ext_vector_type(8)));
typedef float  f32x16  __attribute__((ext_vector_type(16)));

// V layout = PV-fragment image: [b][jt 128][cg 4][seg 4][hi 2][c' 32][e 8]
//   c = cg*64 + (seg>>1)*32 + c',  j = jt*32 + (seg&1)*16 + hi*8 + e.
// A wave (channel group cg) reads fragment seg of tile jt as ONE coalesced
// 1KB load: lane l -> elems (l*8..l*8+7) of segment  (l = hi*32 + c').

// =====================================================================
// Projection: Y[o][n] = sum_c W[o][c] x[c][n] + b[o], bf16 MFMA.
// Item = (b, g, nch64): g<4 -> V row-pairs (o0=g*64 chalf0, o1=+32 chalf1);
// g==4 -> Q (A0, pre-scaled log2e) and K (A1).
// =====================================================================
__global__ __launch_bounds__(256) void proj_kernel(
    const float* __restrict__ x,
    const float* __restrict__ Wq, const float* __restrict__ bq,
    const float* __restrict__ Wk, const float* __restrict__ bk,
    const float* __restrict__ Wv, const float* __restrict__ bv,
    __hip_bfloat16* __restrict__ Qb, __hip_bfloat16* __restrict__ Kb,
    __hip_bfloat16* __restrict__ Vb)
{
    const int t   = threadIdx.x;
    const int l   = t & 63;
    const int w   = t >> 6;
    const int hi  = l >> 5;
    const int col = l & 31;
    const int row = l & 31;

    const int item = blockIdx.x * 4 + w;     // 0..1279
    const int nch  = item & 63;              // 64-n chunk
    const int rest = item >> 6;              // 0..19
    const int g    = rest % 5;
    const int b    = rest / 5;

    const float *W0, *W1, *bs0, *bs1;
    int o0 = 0, o1 = 0;
    if (g < 4) {
        o0 = g * 64; o1 = g * 64 + 32;
        W0 = Wv + (size_t)o0 * NC; W1 = Wv + (size_t)o1 * NC;
        bs0 = bv + o0; bs1 = bv + o1;
    } else {
        W0 = Wq; W1 = Wk; bs0 = bq; bs1 = bk;
    }

    bf16x8 wf0[16], wf1[16];
    const float* Wr0 = W0 + (size_t)row * NC + 8 * hi;
    const float* Wr1 = W1 + (size_t)row * NC + 8 * hi;
    #pragma unroll
    for (int kk = 0; kk < 16; ++kk) {
        float4 a0 = *reinterpret_cast<const float4*>(Wr0 + kk * 16);
        float4 c0 = *reinterpret_cast<const float4*>(Wr0 + kk * 16 + 4);
        float4 a1 = *reinterpret_cast<const float4*>(Wr1 + kk * 16);
        float4 c1 = *reinterpret_cast<const float4*>(Wr1 + kk * 16 + 4);
        bf16x8 f0, f1;
        f0[0] = (__bf16)a0.x; f0[1] = (__bf16)a0.y; f0[2] = (__bf16)a0.z; f0[3] = (__bf16)a0.w;
        f0[4] = (__bf16)c0.x; f0[5] = (__bf16)c0.y; f0[6] = (__bf16)c0.z; f0[7] = (__bf16)c0.w;
        f1[0] = (__bf16)a1.x; f1[1] = (__bf16)a1.y; f1[2] = (__bf16)a1.z; f1[3] = (__bf16)a1.w;
        f1[4] = (__bf16)c1.x; f1[5] = (__bf16)c1.y; f1[6] = (__bf16)c1.z; f1[7] = (__bf16)c1.w;
        wf0[kk] = f0; wf1[kk] = f1;
    }

    #pragma unroll 1
    for (int tile = 0; tile < 2; ++tile) {
        const int n0 = nch * 64 + tile * 32;
        f32x16 acc0, acc1;
        #pragma unroll
        for (int r = 0; r < 16; ++r) { acc0[r] = 0.f; acc1[r] = 0.f; }

        const float* xcol = x + (size_t)b * NC * NPOS + n0 + col;
        #pragma unroll
        for (int kk = 0; kk < 16; ++kk) {
            bf16x8 bf;
            #pragma unroll
            for (int i = 0; i < 8; ++i)
                bf[i] = (__bf16)xcol[(size_t)(kk * 16 + 8 * hi + i) * NPOS];
            acc0 = __builtin_amdgcn_mfma_f32_32x32x16_bf16(wf0[kk], bf, acc0, 0, 0, 0);
            acc1 = __builtin_amdgcn_mfma_f32_32x32x16_bf16(wf1[kk], bf, acc1, 0, 0, 0);
        }

        if (g < 4) {
            // fragment-image store: elem = (col>>4)*512 + ((col>>3)&1)*256
            //                              + orow*8 + (col&7); acc1 seg+2 (+1024)
            __hip_bfloat16* vt = Vb + (size_t)b * NC * NPOS
                                    + (size_t)(n0 >> 5) * 8192 + (size_t)g * 2048
                                    + ((col >> 4) << 9) + (((col >> 3) & 1) << 8)
                                    + (col & 7);
            #pragma unroll
            for (int r = 0; r < 16; ++r) {
                const int orow = (r & 3) + 8 * (r >> 2) + 4 * hi;
                vt[orow * 8]        = __float2bfloat16(acc0[r] + bs0[orow]);
                vt[1024 + orow * 8] = __float2bfloat16(acc1[r] + bs1[orow]);
            }
        } else {
            #pragma unroll
            for (int r = 0; r < 16; ++r) {
                const int orow = (r & 3) + 8 * (r >> 2) + 4 * hi;
                const size_t nidx = (size_t)(b * NPOS) + n0 + col;
                Qb[nidx * NDQK + orow] =
                    __float2bfloat16((acc0[r] + bs0[orow]) * 1.44269504088896f);
                Kb[nidx * NDQK + orow] =
                    __float2bfloat16(acc1[r] + bs1[orow]);
            }
        }
    }
}

// =====================================================================
// Fused flash attention + residual, 32x32x16 MFMA, linear softmax
// (exp2, log2e folded into Q; no online max at |S|<~50).
//
// Wave = 32 q x 64 ch, block = 4 waves (c-split). NO LDS: V fragments
// are read as coalesced 1KB global loads (fragment-image layout) into
// registers, double-buffered one tile ahead alongside K. All ordering
// is plain data dependence — no asm, no syncthreads.
// bid: XCD-pair -> one batch (V[b] = 2MB fits the 4MB per-XCD L2).
// =====================================================================
__global__ __launch_bounds__(256, 2) void attn_kernel(
    const __hip_bfloat16* __restrict__ Qb,
    const __hip_bfloat16* __restrict__ Kb,
    const __hip_bfloat16* __restrict__ Vb,
    const float* __restrict__ x,
    const float* __restrict__ gamma,
    float* __restrict__ out)
{
    const int t   = threadIdx.x;
    const int l   = t & 63;
    const int w   = t >> 6;
    const int hi  = l >> 5;
    const int q   = l & 31;
    const int bx  = blockIdx.x;
    const int b   = (bx >> 1) & 3;               // XCD-pair -> one batch
    const int qb  = ((bx >> 3) << 1) | (bx & 1); // 0..127
    const int q0  = qb * 32;
    const int c0w = w * 64;

    const __bf16* Qp = reinterpret_cast<const __bf16*>(Qb) + (size_t)b * NPOS * NDQK;
    const __bf16* Kp = reinterpret_cast<const __bf16*>(Kb) + (size_t)b * NPOS * NDQK;
    const __bf16* Vp = reinterpret_cast<const __bf16*>(Vb) + (size_t)b * NC * NPOS;

    // swap bits 2<->3 of the A-row index so S lands exactly in PV B-frag order
    const int perm = (q & 0x13) | ((q & 4) << 1) | ((q & 8) >> 1);

    const bf16x8 qf0 = *reinterpret_cast<const bf16x8*>(Qp + (size_t)(q0 + q) * NDQK + 8 * hi);
    const bf16x8 qf1 = *reinterpret_cast<const bf16x8*>(Qp + (size_t)(q0 + q) * NDQK + 16 + 8 * hi);

    const __bf16* Kbase = Kp + (size_t)perm * NDQK + 8 * hi;
    // per-lane V fragment base: wave's channel group + lane slot
    const __bf16* vsrc = Vp + (size_t)w * 2048 + l * 8;

    f32x16 acc0, acc1;
    #pragma unroll
    for (int r = 0; r < 16; ++r) { acc0[r] = 0.f; acc1[r] = 0.f; }
    float lp = 0.f;

    // register double-buffer: current tile's K + V fragments
    bf16x8 kc0 = *reinterpret_cast<const bf16x8*>(Kbase);
    bf16x8 kc1 = *reinterpret_cast<const bf16x8*>(Kbase + 16);
    bf16x8 vc0 = *reinterpret_cast<const bf16x8*>(vsrc);
    bf16x8 vc1 = *reinterpret_cast<const bf16x8*>(vsrc + 512);
    bf16x8 vc2 = *reinterpret_cast<const bf16x8*>(vsrc + 1024);
    bf16x8 vc3 = *reinterpret_cast<const bf16x8*>(vsrc + 1536);

    #pragma unroll 2
    for (int jt = 0; jt < 128; ++jt) {
        // prefetch next tile (K + 4 V fragments), all coalesced
        bf16x8 kn0 = kc0, kn1 = kc1, vn0 = vc0, vn1 = vc1, vn2 = vc2, vn3 = vc3;
        if (jt < 127) {
            const __bf16* kn = Kbase + (size_t)(jt + 1) * 32 * NDQK;
            const __bf16* vn = vsrc + (size_t)(jt + 1) * 8192;
            kn0 = *reinterpret_cast<const bf16x8*>(kn);
            kn1 = *reinterpret_cast<const bf16x8*>(kn + 16);
            vn0 = *reinterpret_cast<const bf16x8*>(vn);
            vn1 = *reinterpret_cast<const bf16x8*>(vn + 512);
            vn2 = *reinterpret_cast<const bf16x8*>(vn + 1024);
            vn3 = *reinterpret_cast<const bf16x8*>(vn + 1536);
        }

        f32x16 s;
        #pragma unroll
        for (int r = 0; r < 16; ++r) s[r] = 0.f;
        s = __builtin_amdgcn_mfma_f32_32x32x16_bf16(kc0, qf0, s, 0, 0, 0);
        s = __builtin_amdgcn_mfma_f32_32x32x16_bf16(kc1, qf1, s, 0, 0, 0);

        float p[16];
        #pragma unroll
        for (int r = 0; r < 16; ++r) p[r] = __builtin_amdgcn_exp2f(s[r]);

        const float s0 = (p[0] + p[1]) + (p[2] + p[3]);
        const float s1 = (p[4] + p[5]) + (p[6] + p[7]);
        const float s2 = (p[8] + p[9]) + (p[10] + p[11]);
        const float s3 = (p[12] + p[13]) + (p[14] + p[15]);
        lp += (s0 + s1) + (s2 + s3);

        bf16x8 pa0, pa1;
        #pragma unroll
        for (int i = 0; i < 8; ++i) { pa0[i] = (__bf16)p[i]; pa1[i] = (__bf16)p[8 + i]; }

        acc0 = __builtin_amdgcn_mfma_f32_32x32x16_bf16(vc0, pa0, acc0, 0, 0, 0);
        acc0 = __builtin_amdgcn_mfma_f32_32x32x16_bf16(vc1, pa1, acc0, 0, 0, 0);
        acc1 = __builtin_amdgcn_mfma_f32_32x32x16_bf16(vc2, pa0, acc1, 0, 0, 0);
        acc1 = __builtin_amdgcn_mfma_f32_32x32x16_bf16(vc3, pa1, acc1, 0, 0, 0);

        kc0 = kn0; kc1 = kn1;
        vc0 = vn0; vc1 = vn1; vc2 = vn2; vc3 = vn3;
    }

    // epilogue: l is lane-local per q after one shfl; direct fused store
    const float lt = lp + __shfl_xor(lp, 32);
    const float gl = gamma[0] / lt;

    #pragma unroll
    for (int r = 0; r < 16; ++r) {
        const int crow = (r & 3) + 8 * (r >> 2) + 4 * hi;
        const size_t g0 = ((size_t)(b * NC + c0w + crow)) * NPOS + q0 + q;
        const size_t g1 = g0 + (size_t)32 * NPOS;
        out[g0] = x[g0] + gl * acc0[r];
        out[g1] = x[g1] + gl * acc1[r];
    }
}

extern "C" void kernel_launch(void* const* d_in, const int* in_sizes, int n_in,
                              void* d_out, int out_size, void* d_ws, size_t ws_size,
                              hipStream_t stream) {
    (void)in_sizes; (void)n_in; (void)out_size; (void)ws_size;
    const float* x     = (const float*)d_in[0];
    const float* Wq    = (const float*)d_in[1];
    const float* bq    = (const float*)d_in[2];
    const float* Wk    = (const float*)d_in[3];
    const float* bk    = (const float*)d_in[4];
    const float* Wv    = (const float*)d_in[5];
    const float* bv    = (const float*)d_in[6];
    const float* gamma = (const float*)d_in[7];
    float* out = (float*)d_out;

    char* ws = (char*)d_ws;
    __hip_bfloat16* Qb = (__hip_bfloat16*)(ws);                    // 1 MB
    __hip_bfloat16* Kb = (__hip_bfloat16*)(ws + (1u << 20));       // 1 MB
    __hip_bfloat16* Vb = (__hip_bfloat16*)(ws + (2u << 20));       // 8 MB (frag-image)

    proj_kernel<<<320, 256, 0, stream>>>(x, Wq, bq, Wk, bk, Wv, bv, Qb, Kb, Vb);
    attn_kernel<<<512, 256, 0, stream>>>(Qb, Kb, Vb, x, gamma, out);
}